// Round 6
// baseline (13087.451 us; speedup 1.0000x reference)
//
#include <hip/hip_runtime.h>
#include <math.h>

#define NRAYS 262144
#define MAXIT 192
#define NEARV 0.2f
#define FARV  2.0f
#define EPSV  0.001f
#define SLOTS 4

// ---------------------------------------------------------------------------
// Kernel 1: sphere march. Persistent waves + atomic work-stealing,
// FOUR rays per lane at 1 wave/SIMD (512-VGPR budget).
// Weight reads stay wave-uniform from const __restrict__ global pointers ->
// scalar s_load (R2-proven). R2/R4/R5 evidence: the march pins at ~52% VALU
// because the SGPR file can't prefetch past one 256B W1 row, leaking ~120cyc
// of scalar-load latency per 128cyc of fma. 4 rays/lane gives 512cyc of
// independent fma per row, fully hiding the prefetch, and cuts SMEM demand
// per FLOP 4x. R4's AGPR-shuffle failure is avoided by the (256,1) bound:
// h1[4][64]=256 VGPR + state ~= 320 < 512, all in arch VGPRs.
// Per-ray fmaf chains are expression-identical to R1/R2 -> bit-exact.
// ---------------------------------------------------------------------------
__global__ __launch_bounds__(256, 1)
void march_kernel(const float* __restrict__ rays,
                  const float* __restrict__ W0, const float* __restrict__ b0,
                  const float* __restrict__ W1, const float* __restrict__ b1,
                  const float* __restrict__ W2, const float* __restrict__ b2,
                  float* __restrict__ t_out, int* __restrict__ hit_out,
                  int* __restrict__ counter)
{
    float ox[SLOTS], oy[SLOTS], oz[SLOTS];
    float rdx[SLOTS], rdy[SLOTS], rdz[SLOTS];
    float cd[SLOTS];
    int   ridx[SLOTS], it[SLOTS];
    bool  has[SLOTS], hit[SLOTS];

    #pragma unroll
    for (int s = 0; s < SLOTS; ++s) {
        ox[s] = oy[s] = oz[s] = rdx[s] = rdy[s] = rdz[s] = 0.f;
        cd[s] = 0.f; ridx[s] = -1; it[s] = 0; has[s] = false; hit[s] = false;
    }
    bool exhausted = false;
    const float b2_0 = b2[0];

    while (true) {
        #pragma unroll
        for (int s = 0; s < SLOTS; ++s) {
            if (!has[s] && !exhausted) {
                int idx = atomicAdd(counter, 1);
                if (idx < NRAYS) {
                    const float* r = rays + (size_t)idx * 6;
                    ox[s] = r[0]; oy[s] = r[1]; oz[s] = r[2];
                    rdx[s] = r[3]; rdy[s] = r[4]; rdz[s] = r[5];
                    cd[s] = NEARV; it[s] = 0; hit[s] = false;
                    has[s] = true; ridx[s] = idx;
                } else {
                    exhausted = true;
                }
            }
        }
        bool any = false;
        #pragma unroll
        for (int s = 0; s < SLOTS; ++s) any = any || has[s];
        if (__ballot(any) == 0ull) break;

        // p = r_o + r_d * cd  (mul then add, matching numpy)
        float px[SLOTS], py[SLOTS], pz[SLOTS];
        #pragma unroll
        for (int s = 0; s < SLOTS; ++s) {
            px[s] = ox[s] + rdx[s] * cd[s];
            py[s] = oy[s] + rdy[s] * cd[s];
            pz[s] = oz[s] + rdz[s] * cd[s];
        }

        float h1[SLOTS][64];
        #pragma unroll
        for (int s = 0; s < SLOTS; ++s)
            #pragma unroll
            for (int j = 0; j < 64; ++j) h1[s][j] = 0.f;

        for (int k = 0; k < 64; ++k) {
            // uniform indices -> scalar loads, shared by all slots
            const float w0x = W0[k], w0y = W0[64 + k], w0z = W0[128 + k];
            const float bb = b0[k];
            float a[SLOTS];
            #pragma unroll
            for (int s = 0; s < SLOTS; ++s) {
                float z = px[s] * w0x + py[s] * w0y + pz[s] * w0z;
                z += bb;
                a[s] = fmaxf(z, 0.f);
            }
            #pragma unroll
            for (int j = 0; j < 64; ++j) {
                const float w = W1[k * 64 + j];
                #pragma unroll
                for (int s = 0; s < SLOTS; ++s)
                    h1[s][j] = fmaf(a[s], w, h1[s][j]);
            }
        }

        float d[SLOTS];
        #pragma unroll
        for (int s = 0; s < SLOTS; ++s) d[s] = 0.f;
        #pragma unroll
        for (int j = 0; j < 64; ++j) {
            const float bj = b1[j];
            const float wj = W2[j * 33];
            #pragma unroll
            for (int s = 0; s < SLOTS; ++s)
                d[s] = fmaf(fmaxf(h1[s][j] + bj, 0.f), wj, d[s]);
        }
        #pragma unroll
        for (int s = 0; s < SLOTS; ++s) d[s] += b2_0;

        #pragma unroll
        for (int s = 0; s < SLOTS; ++s) {
            if (has[s]) {
                ++it[s];
                if (d[s] < EPSV && cd[s] <= FARV) hit[s] = true;
                cd[s] += d[s];
                if (hit[s] || cd[s] > FARV || it[s] >= MAXIT) {
                    t_out[ridx[s]] = cd[s];
                    hit_out[ridx[s]] = hit[s] ? 1 : 0;
                    has[s] = false;
                }
            }
        }
    }
}

// ---------------------------------------------------------------------------
// Kernel 2: shading. One thread per ray. Only hit rays produce output.
// (Unchanged from R1/R2 passing version — bit-exact.)
// ---------------------------------------------------------------------------
__global__ __launch_bounds__(256, 2)
void shade_kernel(const float* __restrict__ rays,
                  const float* __restrict__ W0, const float* __restrict__ b0,
                  const float* __restrict__ W1, const float* __restrict__ b1,
                  const float* __restrict__ W2, const float* __restrict__ b2,
                  const float* __restrict__ RW0, const float* __restrict__ Rb0,
                  const float* __restrict__ RW1, const float* __restrict__ Rb1,
                  const float* __restrict__ t_in, const int* __restrict__ hit_in,
                  float* __restrict__ out)
{
    __shared__ float sW0[3 * 64];
    __shared__ float sb0[64];
    __shared__ float sW1[64 * 64];
    __shared__ float sb1[64];
    __shared__ float sW2T[33 * 64];   // [c][j] = W2[j][c]
    __shared__ float sb2[33];
    __shared__ float sRW0T[64 * 48];  // [u][f] = RW0[f][u], padded 41->48
    __shared__ float sRb0[64];
    __shared__ float sRW1[64 * 3];
    __shared__ float sRb1[3];

    const int tid = threadIdx.x;
    for (int i = tid; i < 3 * 64; i += 256) sW0[i] = W0[i];
    for (int i = tid; i < 64 * 64; i += 256) sW1[i] = W1[i];
    for (int i = tid; i < 33 * 64; i += 256) {
        const int c = i >> 6, j = i & 63;
        sW2T[i] = W2[j * 33 + c];
    }
    for (int i = tid; i < 64 * 41; i += 256) {
        const int u = i / 41, f = i - u * 41;
        sRW0T[u * 48 + f] = RW0[f * 64 + u];
    }
    if (tid < 64) { sb0[tid] = b0[tid]; sb1[tid] = b1[tid]; sRb0[tid] = Rb0[tid]; }
    if (tid < 33) sb2[tid] = b2[tid];
    if (tid < 192) sRW1[tid] = RW1[tid];
    if (tid < 3) sRb1[tid] = Rb1[tid];
    __syncthreads();

    const int i = blockIdx.x * 256 + tid;
    const bool hit = hit_in[i] != 0;

    // Whole-wave skip when nobody hit.
    if (__ballot(hit) == 0ull) {
        out[i * 3 + 0] = 0.f;
        out[i * 3 + 1] = 0.f;
        out[i * 3 + 2] = 0.f;
        return;
    }

    const float* r = rays + (size_t)i * 6;
    const float cd = t_in[i];
    const float ox = r[0], oy = r[1], oz = r[2];
    const float dx = r[3], dy = r[4], dz = r[5];
    const float px = ox + dx * cd;
    const float py = oy + dy * cd;
    const float pz = oz + dz * cd;

    // ---- forward, layer 1 accumulation (h0 recomputed on the fly) ----
    float h1[64];
    #pragma unroll
    for (int j = 0; j < 64; ++j) h1[j] = 0.f;

    for (int k = 0; k < 64; ++k) {
        float z = px * sW0[k] + py * sW0[64 + k] + pz * sW0[128 + k];
        z += sb0[k];
        const float a = fmaxf(z, 0.f);
        #pragma unroll
        for (int j = 0; j < 64; ++j) h1[j] = fmaf(a, sW1[k * 64 + j], h1[j]);
    }
    // rh1 = relu(h1 + b1)  (overwrite in place; rh1==0 <=> z1<=0)
    #pragma unroll
    for (int j = 0; j < 64; ++j) h1[j] = fmaxf(h1[j] + sb1[j], 0.f);

    // ---- latent = out[:,1:33] ----
    float lat[32];
    #pragma unroll
    for (int c = 1; c < 33; ++c) {
        float acc = 0.f;
        #pragma unroll
        for (int j = 0; j < 64; ++j) acc = fmaf(h1[j], sW2T[c * 64 + j], acc);
        lat[c - 1] = acc + sb2[c];
    }

    // ---- backward: gz1 = (z1>0) ? W2[:,0] : 0  (overwrite h1) ----
    #pragma unroll
    for (int j = 0; j < 64; ++j) h1[j] = (h1[j] > 0.f) ? sW2T[j] : 0.f;

    float nx = 0.f, ny = 0.f, nz = 0.f;
    for (int k = 0; k < 64; ++k) {
        float z = px * sW0[k] + py * sW0[64 + k] + pz * sW0[128 + k];
        z += sb0[k];
        float g = 0.f;
        #pragma unroll
        for (int j = 0; j < 64; ++j) g = fmaf(h1[j], sW1[k * 64 + j], g);
        if (z > 0.f) {
            nx = fmaf(g, sW0[k], nx);
            ny = fmaf(g, sW0[64 + k], ny);
            nz = fmaf(g, sW0[128 + k], nz);
        }
    }
    if (!hit) { nx = 0.f; ny = 0.f; nz = 0.f; }

    // ---- render MLP: feat(41) = [pts, r_d, nrm, latent] ----
    float r0 = 0.f, r1 = 0.f, r2 = 0.f;
    for (int u = 0; u < 64; ++u) {
        const float* w = &sRW0T[u * 48];
        float a = px * w[0] + py * w[1] + pz * w[2];
        a = fmaf(dx, w[3], a); a = fmaf(dy, w[4], a); a = fmaf(dz, w[5], a);
        a = fmaf(nx, w[6], a); a = fmaf(ny, w[7], a); a = fmaf(nz, w[8], a);
        #pragma unroll
        for (int q = 0; q < 32; ++q) a = fmaf(lat[q], w[9 + q], a);
        a += sRb0[u];
        const float ru = fmaxf(a, 0.f);
        r0 = fmaf(ru, sRW1[u * 3 + 0], r0);
        r1 = fmaf(ru, sRW1[u * 3 + 1], r1);
        r2 = fmaf(ru, sRW1[u * 3 + 2], r2);
    }
    r0 += sRb1[0]; r1 += sRb1[1]; r2 += sRb1[2];

    const float o0 = 1.f / (1.f + expf(-r0));
    const float o1 = 1.f / (1.f + expf(-r1));
    const float o2 = 1.f / (1.f + expf(-r2));

    out[i * 3 + 0] = hit ? o0 : 0.f;
    out[i * 3 + 1] = hit ? o1 : 0.f;
    out[i * 3 + 2] = hit ? o2 : 0.f;
}

extern "C" void kernel_launch(void* const* d_in, const int* in_sizes, int n_in,
                              void* d_out, int out_size, void* d_ws, size_t ws_size,
                              hipStream_t stream) {
    const float* rays = (const float*)d_in[0];
    const float* W0   = (const float*)d_in[1];
    const float* b0   = (const float*)d_in[2];
    const float* W1   = (const float*)d_in[3];
    const float* b1   = (const float*)d_in[4];
    const float* W2   = (const float*)d_in[5];
    const float* b2   = (const float*)d_in[6];
    const float* RW0  = (const float*)d_in[7];
    const float* Rb0  = (const float*)d_in[8];
    const float* RW1  = (const float*)d_in[9];
    const float* Rb1  = (const float*)d_in[10];

    // Workspace layout: t (N floats) | hit (N ints) | counter (1 int)
    float* t_ws  = (float*)d_ws;
    int* hit_ws  = (int*)d_ws + NRAYS;
    int* ctr     = (int*)d_ws + 2 * NRAYS;

    hipMemsetAsync(ctr, 0, sizeof(int), stream);

    // Persistent march: 1 block/CU (VGPR-bound), 4 rays/lane, work-stealing.
    march_kernel<<<256, 256, 0, stream>>>(rays, W0, b0, W1, b1, W2, b2,
                                          t_ws, hit_ws, ctr);

    shade_kernel<<<NRAYS / 256, 256, 0, stream>>>(rays, W0, b0, W1, b1, W2, b2,
                                                  RW0, Rb0, RW1, Rb1,
                                                  t_ws, hit_ws, (float*)d_out);
}

// Round 7
// 9007.757 us; speedup vs baseline: 1.4529x; 1.4529x over previous
//
#include <hip/hip_runtime.h>
#include <math.h>

#define NRAYS 262144
#define MAXIT 192
#define NEARV 0.2f
#define FARV  2.0f
#define EPSV  0.001f

// ---------------------------------------------------------------------------
// Kernel 0: transpose W1 (64x64) into workspace so the march can read
// COLUMNS of W1 as contiguous wave-uniform s_load rows. Runs once per launch.
// ---------------------------------------------------------------------------
__global__ void transpose_w1(const float* __restrict__ W1, float* __restrict__ W1T)
{
    const int i = blockIdx.x * 256 + threadIdx.x;   // 0..4095
    const int k = i >> 6, j = i & 63;
    W1T[j * 64 + k] = W1[k * 64 + j];
}

// ---------------------------------------------------------------------------
// Kernel 1: sphere march. Persistent waves + atomic work-stealing, 1 ray/lane
// (R2 structure, R2-proven scalar-weight path).
// NEW: j-outer restructure to shrink STATIC code size. R2/R4/R5 all pinned at
// ~45-52% VALU issue efficiency regardless of data-path traffic; the common
// invariant is the ~30KB fully-unrolled loop body vs the 32KB L1 I-cache.
// Here: precompute a[0..63] (layer 0), then a ROLLED 8-iteration jb-loop
// whose ~4KB body computes 8 independent 64-fma dot chains from W1T rows.
// Dynamic inst count unchanged; static hot code ~7KB.
// Bit-exactness: per-j fmaf chain is the same ascending-k chain as R2;
// epilogue d-chain same ascending-j order; a[k] same expressions.
// ---------------------------------------------------------------------------
__global__ __launch_bounds__(256, 4)
void march_kernel(const float* __restrict__ rays,
                  const float* __restrict__ W0, const float* __restrict__ b0,
                  const float* __restrict__ W1T, const float* __restrict__ b1,
                  const float* __restrict__ W2, const float* __restrict__ b2,
                  float* __restrict__ t_out, int* __restrict__ hit_out,
                  int* __restrict__ counter)
{
    float ox = 0.f, oy = 0.f, oz = 0.f, rdx = 0.f, rdy = 0.f, rdz = 0.f;
    float cd = 0.f;
    int ridx = -1, it = 0;
    bool has = false, hit = false, exhausted = false;

    const float b2_0 = b2[0];

    while (true) {
        if (!has && !exhausted) {
            int idx = atomicAdd(counter, 1);
            if (idx < NRAYS) {
                const float* r = rays + (size_t)idx * 6;
                ox = r[0]; oy = r[1]; oz = r[2];
                rdx = r[3]; rdy = r[4]; rdz = r[5];
                cd = NEARV; it = 0; hit = false; has = true; ridx = idx;
            } else {
                exhausted = true;
            }
        }
        if (__ballot(has) == 0ull) break;

        // p = r_o + r_d * cd  (mul then add, matching numpy)
        const float px = ox + rdx * cd;
        const float py = oy + rdy * cd;
        const float pz = oz + rdz * cd;

        // ---- layer 0: a[k], identical expressions to R2 ----
        float a[64];
        #pragma unroll
        for (int k = 0; k < 64; ++k) {
            float z = px * W0[k] + py * W0[64 + k] + pz * W0[128 + k];
            z += b0[k];
            a[k] = fmaxf(z, 0.f);
        }

        // ---- layer 1 + epilogue, j-outer in chunks of 8 (rolled loop) ----
        float d = 0.f;
        #pragma unroll 1
        for (int jb = 0; jb < 64; jb += 8) {
            float h[8];
            #pragma unroll
            for (int u = 0; u < 8; ++u) {
                const float* __restrict__ wrow = W1T + (size_t)(jb + u) * 64;
                float acc = 0.f;
                #pragma unroll
                for (int k = 0; k < 64; ++k)
                    acc = fmaf(a[k], wrow[k], acc);
                h[u] = acc;
            }
            #pragma unroll
            for (int u = 0; u < 8; ++u) {
                const int j = jb + u;
                d = fmaf(fmaxf(h[u] + b1[j], 0.f), W2[j * 33], d);
            }
        }
        d += b2_0;

        if (has) {
            ++it;
            if (d < EPSV && cd <= FARV) hit = true;
            cd += d;
            if (hit || cd > FARV || it >= MAXIT) {
                t_out[ridx] = cd;
                hit_out[ridx] = hit ? 1 : 0;
                has = false;
            }
        }
    }
}

// ---------------------------------------------------------------------------
// Kernel 2: shading. One thread per ray. Only hit rays produce output.
// (Unchanged from R1/R2 passing version — bit-exact.)
// ---------------------------------------------------------------------------
__global__ __launch_bounds__(256, 2)
void shade_kernel(const float* __restrict__ rays,
                  const float* __restrict__ W0, const float* __restrict__ b0,
                  const float* __restrict__ W1, const float* __restrict__ b1,
                  const float* __restrict__ W2, const float* __restrict__ b2,
                  const float* __restrict__ RW0, const float* __restrict__ Rb0,
                  const float* __restrict__ RW1, const float* __restrict__ Rb1,
                  const float* __restrict__ t_in, const int* __restrict__ hit_in,
                  float* __restrict__ out)
{
    __shared__ float sW0[3 * 64];
    __shared__ float sb0[64];
    __shared__ float sW1[64 * 64];
    __shared__ float sb1[64];
    __shared__ float sW2T[33 * 64];   // [c][j] = W2[j][c]
    __shared__ float sb2[33];
    __shared__ float sRW0T[64 * 48];  // [u][f] = RW0[f][u], padded 41->48
    __shared__ float sRb0[64];
    __shared__ float sRW1[64 * 3];
    __shared__ float sRb1[3];

    const int tid = threadIdx.x;
    for (int i = tid; i < 3 * 64; i += 256) sW0[i] = W0[i];
    for (int i = tid; i < 64 * 64; i += 256) sW1[i] = W1[i];
    for (int i = tid; i < 33 * 64; i += 256) {
        const int c = i >> 6, j = i & 63;
        sW2T[i] = W2[j * 33 + c];
    }
    for (int i = tid; i < 64 * 41; i += 256) {
        const int u = i / 41, f = i - u * 41;
        sRW0T[u * 48 + f] = RW0[f * 64 + u];
    }
    if (tid < 64) { sb0[tid] = b0[tid]; sb1[tid] = b1[tid]; sRb0[tid] = Rb0[tid]; }
    if (tid < 33) sb2[tid] = b2[tid];
    if (tid < 192) sRW1[tid] = RW1[tid];
    if (tid < 3) sRb1[tid] = Rb1[tid];
    __syncthreads();

    const int i = blockIdx.x * 256 + tid;
    const bool hit = hit_in[i] != 0;

    // Whole-wave skip when nobody hit.
    if (__ballot(hit) == 0ull) {
        out[i * 3 + 0] = 0.f;
        out[i * 3 + 1] = 0.f;
        out[i * 3 + 2] = 0.f;
        return;
    }

    const float* r = rays + (size_t)i * 6;
    const float cd = t_in[i];
    const float ox = r[0], oy = r[1], oz = r[2];
    const float dx = r[3], dy = r[4], dz = r[5];
    const float px = ox + dx * cd;
    const float py = oy + dy * cd;
    const float pz = oz + dz * cd;

    // ---- forward, layer 1 accumulation (h0 recomputed on the fly) ----
    float h1[64];
    #pragma unroll
    for (int j = 0; j < 64; ++j) h1[j] = 0.f;

    for (int k = 0; k < 64; ++k) {
        float z = px * sW0[k] + py * sW0[64 + k] + pz * sW0[128 + k];
        z += sb0[k];
        const float a = fmaxf(z, 0.f);
        #pragma unroll
        for (int j = 0; j < 64; ++j) h1[j] = fmaf(a, sW1[k * 64 + j], h1[j]);
    }
    // rh1 = relu(h1 + b1)  (overwrite in place; rh1==0 <=> z1<=0)
    #pragma unroll
    for (int j = 0; j < 64; ++j) h1[j] = fmaxf(h1[j] + sb1[j], 0.f);

    // ---- latent = out[:,1:33] ----
    float lat[32];
    #pragma unroll
    for (int c = 1; c < 33; ++c) {
        float acc = 0.f;
        #pragma unroll
        for (int j = 0; j < 64; ++j) acc = fmaf(h1[j], sW2T[c * 64 + j], acc);
        lat[c - 1] = acc + sb2[c];
    }

    // ---- backward: gz1 = (z1>0) ? W2[:,0] : 0  (overwrite h1) ----
    #pragma unroll
    for (int j = 0; j < 64; ++j) h1[j] = (h1[j] > 0.f) ? sW2T[j] : 0.f;

    float nx = 0.f, ny = 0.f, nz = 0.f;
    for (int k = 0; k < 64; ++k) {
        float z = px * sW0[k] + py * sW0[64 + k] + pz * sW0[128 + k];
        z += sb0[k];
        float g = 0.f;
        #pragma unroll
        for (int j = 0; j < 64; ++j) g = fmaf(h1[j], sW1[k * 64 + j], g);
        if (z > 0.f) {
            nx = fmaf(g, sW0[k], nx);
            ny = fmaf(g, sW0[64 + k], ny);
            nz = fmaf(g, sW0[128 + k], nz);
        }
    }
    if (!hit) { nx = 0.f; ny = 0.f; nz = 0.f; }

    // ---- render MLP: feat(41) = [pts, r_d, nrm, latent] ----
    float r0 = 0.f, r1 = 0.f, r2 = 0.f;
    for (int u = 0; u < 64; ++u) {
        const float* w = &sRW0T[u * 48];
        float a = px * w[0] + py * w[1] + pz * w[2];
        a = fmaf(dx, w[3], a); a = fmaf(dy, w[4], a); a = fmaf(dz, w[5], a);
        a = fmaf(nx, w[6], a); a = fmaf(ny, w[7], a); a = fmaf(nz, w[8], a);
        #pragma unroll
        for (int q = 0; q < 32; ++q) a = fmaf(lat[q], w[9 + q], a);
        a += sRb0[u];
        const float ru = fmaxf(a, 0.f);
        r0 = fmaf(ru, sRW1[u * 3 + 0], r0);
        r1 = fmaf(ru, sRW1[u * 3 + 1], r1);
        r2 = fmaf(ru, sRW1[u * 3 + 2], r2);
    }
    r0 += sRb1[0]; r1 += sRb1[1]; r2 += sRb1[2];

    const float o0 = 1.f / (1.f + expf(-r0));
    const float o1 = 1.f / (1.f + expf(-r1));
    const float o2 = 1.f / (1.f + expf(-r2));

    out[i * 3 + 0] = hit ? o0 : 0.f;
    out[i * 3 + 1] = hit ? o1 : 0.f;
    out[i * 3 + 2] = hit ? o2 : 0.f;
}

extern "C" void kernel_launch(void* const* d_in, const int* in_sizes, int n_in,
                              void* d_out, int out_size, void* d_ws, size_t ws_size,
                              hipStream_t stream) {
    const float* rays = (const float*)d_in[0];
    const float* W0   = (const float*)d_in[1];
    const float* b0   = (const float*)d_in[2];
    const float* W1   = (const float*)d_in[3];
    const float* b1   = (const float*)d_in[4];
    const float* W2   = (const float*)d_in[5];
    const float* b2   = (const float*)d_in[6];
    const float* RW0  = (const float*)d_in[7];
    const float* Rb0  = (const float*)d_in[8];
    const float* RW1  = (const float*)d_in[9];
    const float* Rb1  = (const float*)d_in[10];

    // Workspace layout: t (N floats) | hit (N ints) | counter+pad (16) | W1T (4096)
    float* t_ws  = (float*)d_ws;
    int* hit_ws  = (int*)d_ws + NRAYS;
    int* ctr     = (int*)d_ws + 2 * NRAYS;
    float* W1T   = (float*)d_ws + 2 * NRAYS + 16;

    hipMemsetAsync(ctr, 0, sizeof(int), stream);

    transpose_w1<<<16, 256, 0, stream>>>(W1, W1T);

    // Persistent march: 4 blocks/CU, 1 ray/lane, work-stealing.
    march_kernel<<<1024, 256, 0, stream>>>(rays, W0, b0, W1T, b1, W2, b2,
                                           t_ws, hit_ws, ctr);

    shade_kernel<<<NRAYS / 256, 256, 0, stream>>>(rays, W0, b0, W1, b1, W2, b2,
                                                  RW0, Rb0, RW1, Rb1,
                                                  t_ws, hit_ws, (float*)d_out);
}